// Round 1
// baseline (855.522 us; speedup 1.0000x reference)
//
#include <hip/hip_runtime.h>
#include <utility>

#define HH 20

typedef float v2f __attribute__((ext_vector_type(2)));

// Raw v_rcp_f32 (~1 ulp); harness threshold 1.9e-3.
__device__ __forceinline__ float fast_rcp(float x) { return __builtin_amdgcn_rcpf(x); }
__device__ __forceinline__ float fsigmoid(float x) { return fast_rcp(1.0f + __expf(-x)); }
__device__ __forceinline__ float ftanh(float x) {
    float e = __expf(2.0f * x);
    return 1.0f - 2.0f * fast_rcp(e + 1.0f);
}

// v_pk_fma_f32: two independent IEEE fp32 FMAs per instruction.
__device__ __forceinline__ v2f fma2(v2f a, v2f b, v2f c) {
#if __has_builtin(__builtin_elementwise_fma)
    return __builtin_elementwise_fma(a, b, c);
#else
    v2f r; r.x = fmaf(a.x, b.x, c.x); r.y = fmaf(a.y, b.y, c.y); return r;
#endif
}

// ---- K-paired dot product against wave-uniform weights ----------------------
// W + base is wave-uniform (compile-time constants + laundered-0 z), so the
// compiler proves uniformity and emits s_load; v_pk_fma_f32 then takes the
// SGPR pair (w[2j], w[2j+1]) directly as src. p[] holds the per-lane
// (k even, k odd) operand pairs. Weight pairs are contiguous in the ORIGINAL
// row-major [4H, IN] layout, so no repack/staging is needed at all.
template <int NP, size_t... J>
__device__ __forceinline__ v2f dot2i(const float* __restrict__ W, int base,
                                     const v2f (&p)[NP], v2f acc, std::index_sequence<J...>) {
    ((acc = fma2(*(const v2f*)(W + base + 2 * (int)J), p[J], acc)), ...);
    return acc;
}
template <int NP>
__device__ __forceinline__ v2f dot2(const float* __restrict__ W, int base,
                                    const v2f (&p)[NP], v2f acc) {
    return dot2i<NP>(W, base, p, acc, std::make_index_sequence<NP>{});
}

template <int N, size_t... J>
__device__ __forceinline__ void mkpairs_i(const float (&a)[N], v2f (&p)[N / 2],
                                          std::index_sequence<J...>) {
    ((p[J] = v2f{a[2 * J], a[2 * J + 1]}), ...);
}
template <int N>
__device__ __forceinline__ void mkpairs(const float (&a)[N], v2f (&p)[N / 2]) {
    mkpairs_i<N>(a, p, std::make_index_sequence<N / 2>{});
}

// One LSTM unit, all 4 gates per lane (no cross-lane traffic, no LDS).
// Gate row blocks in PyTorch order: i=0, f=1, g=2, o=3.
template <int IN, int U>
__device__ __forceinline__ void unitK(const float* __restrict__ Wih, const float* __restrict__ Whh,
                                      const float* __restrict__ bb, int z,
                                      const v2f (&xp)[IN / 2], const v2f (&hp)[HH / 2],
                                      float (&c)[HH], float (&hn)[HH]) {
    const v2f zz = {0.f, 0.f};
    v2f ai = dot2<IN / 2>(Wih, z + (0 * HH + U) * IN, xp, zz);
    v2f af = dot2<IN / 2>(Wih, z + (1 * HH + U) * IN, xp, zz);
    v2f ag = dot2<IN / 2>(Wih, z + (2 * HH + U) * IN, xp, zz);
    v2f ao = dot2<IN / 2>(Wih, z + (3 * HH + U) * IN, xp, zz);
    ai = dot2<HH / 2>(Whh, z + (0 * HH + U) * HH, hp, ai);
    af = dot2<HH / 2>(Whh, z + (1 * HH + U) * HH, hp, af);
    ag = dot2<HH / 2>(Whh, z + (2 * HH + U) * HH, hp, ag);
    ao = dot2<HH / 2>(Whh, z + (3 * HH + U) * HH, hp, ao);
    float gi = ai.x + ai.y + bb[z + 0 * HH + U];
    float gf = af.x + af.y + bb[z + 1 * HH + U];
    float gg = ag.x + ag.y + bb[z + 2 * HH + U];
    float go = ao.x + ao.y + bb[z + 3 * HH + U];
    float si = fsigmoid(gi);
    float sf = fsigmoid(gf);
    float so = fsigmoid(go);
    float tg = ftanh(gg);
    float cn = fmaf(sf, c[U], si * tg);
    c[U] = cn;
    hn[U] = so * ftanh(cn);
}

template <int IN, size_t... U>
__device__ __forceinline__ void cellK_u(const float* __restrict__ Wih, const float* __restrict__ Whh,
                                        const float* __restrict__ bb, int z,
                                        const v2f (&xp)[IN / 2], float (&h)[HH], float (&c)[HH],
                                        std::index_sequence<U...>) {
    v2f hp[HH / 2];
    mkpairs<HH>(h, hp);
    float hn[HH];
    (unitK<IN, (int)U>(Wih, Whh, bb, z, xp, hp, c, hn), ...);
    ((h[U] = hn[U]), ...);
}
template <int IN>
__device__ __forceinline__ void cellK(const float* __restrict__ Wih, const float* __restrict__ Whh,
                                      const float* __restrict__ bb, int z,
                                      const float (&x)[IN], float (&h)[HH], float (&c)[HH]) {
    v2f xp[IN / 2];
    mkpairs<IN>(x, xp);
    cellK_u<IN>(Wih, Whh, bb, z, xp, h, c, std::make_index_sequence<HH>{});
}

// ---- MLP head: same K-paired uniform-weight pattern -------------------------
template <int NP>
__device__ __forceinline__ float rowdot(const float* __restrict__ W, int base,
                                        const v2f (&p)[NP], float b) {
    const v2f zz = {0.f, 0.f};
    v2f a = dot2<NP>(W, base, p, zz);
    return a.x + a.y + b;
}
template <int NP, int LD, size_t... J>
__device__ __forceinline__ void mlp_layer(const float* __restrict__ W, const float* __restrict__ bv,
                                          int z, const v2f (&p)[NP], float (&o)[10],
                                          std::index_sequence<J...>) {
    ((o[J] = fmaxf(rowdot<NP>(W, z + (int)J * LD, p, bv[z + (int)J]), 0.f)), ...);
}

__global__ void __launch_bounds__(256, 2) lstm_ar_kernel(
    const float* __restrict__ y_past, const float* __restrict__ x_past,
    const float* __restrict__ u_past, const float* __restrict__ s_past,
    const float* __restrict__ u_future,
    const float* __restrict__ Wih1_0, const float* __restrict__ Whh1_0, const float* __restrict__ b1_0,
    const float* __restrict__ Wih1_1, const float* __restrict__ Whh1_1, const float* __restrict__ b1_1,
    const float* __restrict__ Wih2_0, const float* __restrict__ Whh2_0, const float* __restrict__ b2_0,
    const float* __restrict__ Wih2_1, const float* __restrict__ Whh2_1, const float* __restrict__ b2_1,
    const float* __restrict__ fW1, const float* __restrict__ fb1,
    const float* __restrict__ fW2, const float* __restrict__ fb2,
    const float* __restrict__ fW3, const float* __restrict__ fb3,
    float* __restrict__ out, int B) {
    const int e = blockIdx.x * 256 + threadIdx.x;
    if (e >= B) return;  // never taken (B % 256 == 0)

    // own-element state only: 80 registers
    float h0[HH], c0[HH], h1[HH], c1[HH];
    {
        auto zero = [&](auto... u) {
            ((h0[u] = 0.f, c0[u] = 0.f, h1[u] = 0.f, c1[u] = 0.f), ...);
        };
        zero(0, 1, 2, 3, 4, 5, 6, 7, 8, 9, 10, 11, 12, 13, 14, 15, 16, 17, 18, 19);
    }

    // ---- encoder over lookback T=8 (input = concat[y,x,u,s] = 16 feats) ----
#pragma clang loop unroll(disable)
    for (int t = 0; t < 8; ++t) {
        int z = 0;
        asm volatile("" : "+s"(z));  // laundered 0: blocks cross-t s_load hoisting
        float x[16];
        x[0] = y_past[e * 8 + t];
        {
            const float4* p = (const float4*)(x_past + (size_t)(e * 8 + t) * 8);
            float4 a0 = p[0], a1 = p[1];
            x[1] = a0.x; x[2] = a0.y; x[3] = a0.z; x[4] = a0.w;
            x[5] = a1.x; x[6] = a1.y; x[7] = a1.z; x[8] = a1.w;
        }
        {
            const float4* p = (const float4*)(u_past + (size_t)(e * 8 + t) * 4);
            float4 a0 = p[0];
            x[9] = a0.x; x[10] = a0.y; x[11] = a0.z; x[12] = a0.w;
        }
        {
            const float* p = s_past + (size_t)(e * 8 + t) * 3;
            x[13] = p[0]; x[14] = p[1]; x[15] = p[2];
        }
        cellK<16>(Wih1_0, Whh1_0, b1_0, z, x, h0, c0);
        cellK<HH>(Wih1_1, Whh1_1, b1_1, z, h0, h1, c1);
    }

    // ---- decoder over lookahead T=4 (input = u_future, 4 feats) + MLP head ----
#pragma clang loop unroll(disable)
    for (int t = 0; t < 4; ++t) {
        int z = 0;
        asm volatile("" : "+s"(z));
        float x[4];
        {
            const float4* p = (const float4*)(u_future + (size_t)(e * 4 + t) * 4);
            float4 a0 = p[0];
            x[0] = a0.x; x[1] = a0.y; x[2] = a0.z; x[3] = a0.w;
        }
        cellK<4>(Wih2_0, Whh2_0, b2_0, z, x, h0, c0);
        cellK<HH>(Wih2_1, Whh2_1, b2_1, z, h0, h1, c1);

        // FCNN 20 -> 10 -> 10 -> 1
        v2f hp1[HH / 2];
        mkpairs<HH>(h1, hp1);
        float z1[10], z2[10];
        mlp_layer<HH / 2, HH>(fW1, fb1, z, hp1, z1, std::make_index_sequence<10>{});
        v2f zp1[5];
        mkpairs<10>(z1, zp1);
        mlp_layer<5, 10>(fW2, fb2, z, zp1, z2, std::make_index_sequence<10>{});
        v2f zp2[5];
        mkpairs<10>(z2, zp2);
        float o = rowdot<5>(fW3, z + 0, zp2, fb3[z + 0]);
        out[e * 4 + t] = o;
    }
}

extern "C" void kernel_launch(void* const* d_in, const int* in_sizes, int n_in,
                              void* d_out, int out_size, void* d_ws, size_t ws_size,
                              hipStream_t stream) {
    (void)n_in; (void)d_ws; (void)ws_size;
    const float* y_past   = (const float*)d_in[0];
    const float* x_past   = (const float*)d_in[1];
    const float* u_past   = (const float*)d_in[2];
    const float* s_past   = (const float*)d_in[3];
    const float* u_future = (const float*)d_in[4];
    const float* Wih1_0 = (const float*)d_in[5];
    const float* Whh1_0 = (const float*)d_in[6];
    const float* b1_0   = (const float*)d_in[7];
    const float* Wih1_1 = (const float*)d_in[8];
    const float* Whh1_1 = (const float*)d_in[9];
    const float* b1_1   = (const float*)d_in[10];
    const float* Wih2_0 = (const float*)d_in[11];
    const float* Whh2_0 = (const float*)d_in[12];
    const float* b2_0   = (const float*)d_in[13];
    const float* Wih2_1 = (const float*)d_in[14];
    const float* Whh2_1 = (const float*)d_in[15];
    const float* b2_1   = (const float*)d_in[16];
    const float* fW1 = (const float*)d_in[17];
    const float* fb1 = (const float*)d_in[18];
    const float* fW2 = (const float*)d_in[19];
    const float* fb2 = (const float*)d_in[20];
    const float* fW3 = (const float*)d_in[21];
    const float* fb3 = (const float*)d_in[22];
    float* out = (float*)d_out;

    int B = in_sizes[0] / 8;  // y_past is [B,8,1]
    (void)out_size;

    dim3 block(256);
    dim3 grid((B + 255) / 256);
    lstm_ar_kernel<<<grid, block, 0, stream>>>(
        y_past, x_past, u_past, s_past, u_future,
        Wih1_0, Whh1_0, b1_0, Wih1_1, Whh1_1, b1_1,
        Wih2_0, Whh2_0, b2_0, Wih2_1, Whh2_1, b2_1,
        fW1, fb1, fW2, fb2, fW3, fb3, out, B);
}

// Round 2
// 779.080 us; speedup vs baseline: 1.0981x; 1.0981x over previous
//
#include <hip/hip_runtime.h>
#include <utility>

#define HH 20

typedef float v2f __attribute__((ext_vector_type(2)));

// Raw v_rcp_f32 (~1 ulp); harness threshold 1.9e-3.
__device__ __forceinline__ float fast_rcp(float x) { return __builtin_amdgcn_rcpf(x); }
__device__ __forceinline__ float fsigmoid(float x) { return fast_rcp(1.0f + __expf(-x)); }
__device__ __forceinline__ float ftanh(float x) {
    float e = __expf(2.0f * x);
    return 1.0f - 2.0f * fast_rcp(e + 1.0f);
}

// v_pk_fma_f32: two independent IEEE fp32 FMAs per instruction.
__device__ __forceinline__ v2f fma2(v2f a, v2f b, v2f c) {
#if __has_builtin(__builtin_elementwise_fma)
    return __builtin_elementwise_fma(a, b, c);
#else
    v2f r; r.x = fmaf(a.x, b.x, c.x); r.y = fmaf(a.y, b.y, c.y); return r;
#endif
}
__device__ __forceinline__ v2f splat(float w) { return v2f{w, w}; }
__device__ __forceinline__ v2f relu2(v2f a) { return v2f{fmaxf(a.x, 0.f), fmaxf(a.y, 0.f)}; }

// ---- LDS weight arena: contiguous, UNPADDED ---------------------------------
// Every inner-loop LDS read is wave-uniform (all lanes broadcast the same
// address) -> no bank conflicts possible, no pads needed. Row strides are
// 16/20/4 floats = 64/80/16 B, all 16B-aligned -> ds_read_b128 legal.
constexpr int W_Wih1_0 = 0;
constexpr int W_Whh1_0 = W_Wih1_0 + 4 * HH * 16;   // 1280
constexpr int W_b1_0   = W_Whh1_0 + 4 * HH * HH;   // 2880
constexpr int W_Wih1_1 = W_b1_0 + 4 * HH;          // 2960
constexpr int W_Whh1_1 = W_Wih1_1 + 4 * HH * HH;   // 4560
constexpr int W_b1_1   = W_Whh1_1 + 4 * HH * HH;   // 6160
constexpr int W_Wih2_0 = W_b1_1 + 4 * HH;          // 6240
constexpr int W_Whh2_0 = W_Wih2_0 + 4 * HH * 4;    // 6560
constexpr int W_b2_0   = W_Whh2_0 + 4 * HH * HH;   // 8160
constexpr int W_Wih2_1 = W_b2_0 + 4 * HH;          // 8240
constexpr int W_Whh2_1 = W_Wih2_1 + 4 * HH * HH;   // 9840
constexpr int W_b2_1   = W_Whh2_1 + 4 * HH * HH;   // 11440
constexpr int W_fW1    = W_b2_1 + 4 * HH;          // 11520
constexpr int W_fb1    = W_fW1 + 200;              // 11720
constexpr int W_fW2    = W_fb1 + 10;               // 11730
constexpr int W_fb2    = W_fW2 + 100;              // 11830
constexpr int W_fW3    = W_fb2 + 10;               // 11840
constexpr int W_fb3    = W_fW3 + 10;               // 11850
constexpr int LDS_TOT  = W_fb3 + 1;                // 11851 floats = 47.4 KB

// One gate-row dot: float4 LDS chunks (ds_read_b128, uniform broadcast), each
// chunk feeds 4 pk-fma = 8 scalar FMAs (4 weights x 2 elements).
template <int IN, size_t... R>
__device__ __forceinline__ v2f gdot_i(const float (&sm)[LDS_TOT], int base,
                                      const v2f (&p)[IN], v2f acc, std::index_sequence<R...>) {
    (([&] {
        float4 w = *(const float4*)&sm[base + 4 * (int)R];
        acc = fma2(splat(w.x), p[4 * R + 0], acc);
        acc = fma2(splat(w.y), p[4 * R + 1], acc);
        acc = fma2(splat(w.z), p[4 * R + 2], acc);
        acc = fma2(splat(w.w), p[4 * R + 3], acc);
    }()), ...);
    return acc;
}
template <int IN>
__device__ __forceinline__ v2f gdot(const float (&sm)[LDS_TOT], int base,
                                    const v2f (&p)[IN], v2f acc) {
    return gdot_i<IN>(sm, base, p, acc, std::make_index_sequence<IN / 4>{});
}

// One LSTM unit: all 4 gates, 2 elements per lane (v2f halves).
// Gate row blocks in PyTorch order: i=0, f=1, g=2, o=3.
template <int IN, int WIH, int WHH, int BOFF, int U>
__device__ __forceinline__ void unitK(const float (&sm)[LDS_TOT], int z,
                                      const v2f (&xp)[IN], const v2f (&hp)[HH],
                                      v2f (&c)[HH], v2f (&hn)[HH]) {
    v2f ai = splat(sm[z + BOFF + 0 * HH + U]);
    v2f af = splat(sm[z + BOFF + 1 * HH + U]);
    v2f ag = splat(sm[z + BOFF + 2 * HH + U]);
    v2f ao = splat(sm[z + BOFF + 3 * HH + U]);
    ai = gdot<IN>(sm, z + WIH + (0 * HH + U) * IN, xp, ai);
    af = gdot<IN>(sm, z + WIH + (1 * HH + U) * IN, xp, af);
    ag = gdot<IN>(sm, z + WIH + (2 * HH + U) * IN, xp, ag);
    ao = gdot<IN>(sm, z + WIH + (3 * HH + U) * IN, xp, ao);
    ai = gdot<HH>(sm, z + WHH + (0 * HH + U) * HH, hp, ai);
    af = gdot<HH>(sm, z + WHH + (1 * HH + U) * HH, hp, af);
    ag = gdot<HH>(sm, z + WHH + (2 * HH + U) * HH, hp, ag);
    ao = gdot<HH>(sm, z + WHH + (3 * HH + U) * HH, hp, ao);
    float si0 = fsigmoid(ai.x), si1 = fsigmoid(ai.y);
    float sf0 = fsigmoid(af.x), sf1 = fsigmoid(af.y);
    float tg0 = ftanh(ag.x),    tg1 = ftanh(ag.y);
    float so0 = fsigmoid(ao.x), so1 = fsigmoid(ao.y);
    float cn0 = fmaf(sf0, c[U].x, si0 * tg0);
    float cn1 = fmaf(sf1, c[U].y, si1 * tg1);
    c[U] = v2f{cn0, cn1};
    hn[U] = v2f{so0 * ftanh(cn0), so1 * ftanh(cn1)};
}

template <int IN, int WIH, int WHH, int BOFF, size_t... U>
__device__ __forceinline__ void cellK_impl(const float (&sm)[LDS_TOT], int z,
                                           const v2f (&xp)[IN], v2f (&h)[HH], v2f (&c)[HH],
                                           std::index_sequence<U...>) {
    v2f hn[HH];
    (unitK<IN, WIH, WHH, BOFF, (int)U>(sm, z, xp, h, c, hn), ...);
    ((h[U] = hn[U]), ...);
}
template <int IN, int WIH, int WHH, int BOFF>
__device__ __forceinline__ void cellK(const float (&sm)[LDS_TOT], int z,
                                      const v2f (&xp)[IN], v2f (&h)[HH], v2f (&c)[HH]) {
    cellK_impl<IN, WIH, WHH, BOFF>(sm, z, xp, h, c, std::make_index_sequence<HH>{});
}

// ---- MLP head: scalar-weight (uniform b32) x v2f-feature dots ---------------
template <int NF, size_t... K>
__device__ __forceinline__ v2f vdot_i(const float (&sm)[LDS_TOT], int base,
                                      const v2f (&p)[NF], v2f acc, std::index_sequence<K...>) {
    ((acc = fma2(splat(sm[base + (int)K]), p[K], acc)), ...);
    return acc;
}
template <int NF>
__device__ __forceinline__ v2f vdot(const float (&sm)[LDS_TOT], int base,
                                    const v2f (&p)[NF], v2f acc) {
    return vdot_i<NF>(sm, base, p, acc, std::make_index_sequence<NF>{});
}
template <int WOFF, int BOFF, int NF, int LD, size_t... J>
__device__ __forceinline__ void mlp_layer(const float (&sm)[LDS_TOT], int z,
                                          const v2f (&p)[NF], v2f (&o)[10],
                                          std::index_sequence<J...>) {
    ((o[J] = relu2(vdot<NF>(sm, z + WOFF + (int)J * LD, p,
                            splat(sm[z + BOFF + (int)J])))), ...);
}

__global__ void __launch_bounds__(128, 1) lstm_ar_kernel(
    const float* __restrict__ y_past, const float* __restrict__ x_past,
    const float* __restrict__ u_past, const float* __restrict__ s_past,
    const float* __restrict__ u_future,
    const float* __restrict__ Wih1_0, const float* __restrict__ Whh1_0, const float* __restrict__ b1_0,
    const float* __restrict__ Wih1_1, const float* __restrict__ Whh1_1, const float* __restrict__ b1_1,
    const float* __restrict__ Wih2_0, const float* __restrict__ Whh2_0, const float* __restrict__ b2_0,
    const float* __restrict__ Wih2_1, const float* __restrict__ Whh2_1, const float* __restrict__ b2_1,
    const float* __restrict__ fW1, const float* __restrict__ fb1,
    const float* __restrict__ fW2, const float* __restrict__ fb2,
    const float* __restrict__ fW3, const float* __restrict__ fb3,
    float* __restrict__ out, int B) {
    __shared__ __align__(16) float smem[LDS_TOT];
    const int tid = threadIdx.x;

    auto stage = [&](const float* src, int off, int n) {
        for (int i = tid; i < n; i += 128) smem[off + i] = src[i];
    };
    stage(Wih1_0, W_Wih1_0, 4 * HH * 16);
    stage(Whh1_0, W_Whh1_0, 4 * HH * HH);
    stage(b1_0, W_b1_0, 4 * HH);
    stage(Wih1_1, W_Wih1_1, 4 * HH * HH);
    stage(Whh1_1, W_Whh1_1, 4 * HH * HH);
    stage(b1_1, W_b1_1, 4 * HH);
    stage(Wih2_0, W_Wih2_0, 4 * HH * 4);
    stage(Whh2_0, W_Whh2_0, 4 * HH * HH);
    stage(b2_0, W_b2_0, 4 * HH);
    stage(Wih2_1, W_Wih2_1, 4 * HH * HH);
    stage(Whh2_1, W_Whh2_1, 4 * HH * HH);
    stage(b2_1, W_b2_1, 4 * HH);
    stage(fW1, W_fW1, 200);
    stage(fb1, W_fb1, 10);
    stage(fW2, W_fW2, 100);
    stage(fb2, W_fb2, 10);
    stage(fW3, W_fW3, 10);
    stage(fb3, W_fb3, 1);
    __syncthreads();

    const int half = B >> 1;                    // B % 256 == 0
    const int g = blockIdx.x * 128 + tid;
    if (g >= half) return;                      // never taken
    const int e0 = g;                           // element pair: (g, g + B/2)
    const int e1 = g + half;                    // both streams stride-1 coalesced

    // 2-element state as v2f arrays: 160 VGPRs. At 1 wave/SIMD the budget is
    // 512 VGPRs, so the whole working set stays register-resident.
    v2f h0[HH], c0[HH], h1[HH], c1[HH];
    {
        auto zero = [&](auto... u) {
            ((h0[u] = v2f{0.f, 0.f}, c0[u] = v2f{0.f, 0.f},
              h1[u] = v2f{0.f, 0.f}, c1[u] = v2f{0.f, 0.f}), ...);
        };
        zero(0, 1, 2, 3, 4, 5, 6, 7, 8, 9, 10, 11, 12, 13, 14, 15, 16, 17, 18, 19);
    }

    // ---- encoder over lookback T=8 (input = concat[y,x,u,s] = 16 feats) ----
#pragma clang loop unroll(disable)
    for (int t = 0; t < 8; ++t) {
        int z = 0;
        asm volatile("" : "+s"(z));  // laundered 0: blocks cross-t hoisting
        v2f xp[16];
        {
            float a = y_past[e0 * 8 + t];
            float b = y_past[e1 * 8 + t];
            xp[0] = v2f{a, b};
        }
        {
            const float4* pa = (const float4*)(x_past + (size_t)(e0 * 8 + t) * 8);
            const float4* pb = (const float4*)(x_past + (size_t)(e1 * 8 + t) * 8);
            float4 a0 = pa[0], a1 = pa[1], b0 = pb[0], b1 = pb[1];
            xp[1] = v2f{a0.x, b0.x}; xp[2] = v2f{a0.y, b0.y};
            xp[3] = v2f{a0.z, b0.z}; xp[4] = v2f{a0.w, b0.w};
            xp[5] = v2f{a1.x, b1.x}; xp[6] = v2f{a1.y, b1.y};
            xp[7] = v2f{a1.z, b1.z}; xp[8] = v2f{a1.w, b1.w};
        }
        {
            const float4* pa = (const float4*)(u_past + (size_t)(e0 * 8 + t) * 4);
            const float4* pb = (const float4*)(u_past + (size_t)(e1 * 8 + t) * 4);
            float4 a0 = pa[0], b0 = pb[0];
            xp[9]  = v2f{a0.x, b0.x}; xp[10] = v2f{a0.y, b0.y};
            xp[11] = v2f{a0.z, b0.z}; xp[12] = v2f{a0.w, b0.w};
        }
        {
            const float* pa = s_past + (size_t)(e0 * 8 + t) * 3;
            const float* pb = s_past + (size_t)(e1 * 8 + t) * 3;
            xp[13] = v2f{pa[0], pb[0]};
            xp[14] = v2f{pa[1], pb[1]};
            xp[15] = v2f{pa[2], pb[2]};
        }
        cellK<16, W_Wih1_0, W_Whh1_0, W_b1_0>(smem, z, xp, h0, c0);
        cellK<HH, W_Wih1_1, W_Whh1_1, W_b1_1>(smem, z, h0, h1, c1);
    }

    // ---- decoder over lookahead T=4 (input = u_future, 4 feats) + MLP head ----
#pragma clang loop unroll(disable)
    for (int t = 0; t < 4; ++t) {
        int z = 0;
        asm volatile("" : "+s"(z));
        v2f xp[4];
        {
            const float4* pa = (const float4*)(u_future + (size_t)(e0 * 4 + t) * 4);
            const float4* pb = (const float4*)(u_future + (size_t)(e1 * 4 + t) * 4);
            float4 a0 = pa[0], b0 = pb[0];
            xp[0] = v2f{a0.x, b0.x}; xp[1] = v2f{a0.y, b0.y};
            xp[2] = v2f{a0.z, b0.z}; xp[3] = v2f{a0.w, b0.w};
        }
        cellK<4, W_Wih2_0, W_Whh2_0, W_b2_0>(smem, z, xp, h0, c0);
        cellK<HH, W_Wih2_1, W_Whh2_1, W_b2_1>(smem, z, h0, h1, c1);

        // FCNN 20 -> 10 -> 10 -> 1 on both elements (v2f halves)
        v2f z1[10], z2[10];
        mlp_layer<W_fW1, W_fb1, HH, HH>(smem, z, h1, z1, std::make_index_sequence<10>{});
        mlp_layer<W_fW2, W_fb2, 10, 10>(smem, z, z1, z2, std::make_index_sequence<10>{});
        v2f o = vdot<10>(smem, z + W_fW3, z2, splat(smem[z + W_fb3]));
        out[e0 * 4 + t] = o.x;
        out[e1 * 4 + t] = o.y;
    }
}

extern "C" void kernel_launch(void* const* d_in, const int* in_sizes, int n_in,
                              void* d_out, int out_size, void* d_ws, size_t ws_size,
                              hipStream_t stream) {
    (void)n_in; (void)d_ws; (void)ws_size;
    const float* y_past   = (const float*)d_in[0];
    const float* x_past   = (const float*)d_in[1];
    const float* u_past   = (const float*)d_in[2];
    const float* s_past   = (const float*)d_in[3];
    const float* u_future = (const float*)d_in[4];
    const float* Wih1_0 = (const float*)d_in[5];
    const float* Whh1_0 = (const float*)d_in[6];
    const float* b1_0   = (const float*)d_in[7];
    const float* Wih1_1 = (const float*)d_in[8];
    const float* Whh1_1 = (const float*)d_in[9];
    const float* b1_1   = (const float*)d_in[10];
    const float* Wih2_0 = (const float*)d_in[11];
    const float* Whh2_0 = (const float*)d_in[12];
    const float* b2_0   = (const float*)d_in[13];
    const float* Wih2_1 = (const float*)d_in[14];
    const float* Whh2_1 = (const float*)d_in[15];
    const float* b2_1   = (const float*)d_in[16];
    const float* fW1 = (const float*)d_in[17];
    const float* fb1 = (const float*)d_in[18];
    const float* fW2 = (const float*)d_in[19];
    const float* fb2 = (const float*)d_in[20];
    const float* fW3 = (const float*)d_in[21];
    const float* fb3 = (const float*)d_in[22];
    float* out = (float*)d_out;

    int B = in_sizes[0] / 8;  // y_past is [B,8,1]
    (void)out_size;

    int nthreads = B / 2;     // 2 elements per thread
    dim3 block(128);
    dim3 grid((nthreads + 127) / 128);
    lstm_ar_kernel<<<grid, block, 0, stream>>>(
        y_past, x_past, u_past, s_past, u_future,
        Wih1_0, Whh1_0, b1_0, Wih1_1, Whh1_1, b1_1,
        Wih2_0, Whh2_0, b2_0, Wih2_1, Whh2_1, b2_1,
        fW1, fb1, fW2, fb2, fW3, fb3, out, B);
}

// Round 3
// 631.131 us; speedup vs baseline: 1.3555x; 1.2344x over previous
//
#include <hip/hip_runtime.h>
#include <utility>

#define HH 20

typedef float v2f __attribute__((ext_vector_type(2)));

// Raw v_rcp_f32 (~1 ulp); harness threshold 1.9e-3.
__device__ __forceinline__ float fast_rcp(float x) { return __builtin_amdgcn_rcpf(x); }
__device__ __forceinline__ float fsigmoid(float x) { return fast_rcp(1.0f + __expf(-x)); }
__device__ __forceinline__ float ftanh(float x) {
    float e = __expf(2.0f * x);
    return 1.0f - 2.0f * fast_rcp(e + 1.0f);
}
// DPP quad_perm [1,0,3,2]: swap values across adjacent lane pairs (VALU pipe).
__device__ __forceinline__ float pswap(float v) {
    return __int_as_float(__builtin_amdgcn_mov_dpp(__float_as_int(v), 0xB1, 0xF, 0xF, true));
}
// v_pk_fma_f32: two independent IEEE fp32 FMAs per instruction.
__device__ __forceinline__ v2f fma2(v2f a, v2f b, v2f c) {
#if __has_builtin(__builtin_elementwise_fma)
    return __builtin_elementwise_fma(a, b, c);
#else
    v2f r; r.x = fmaf(a.x, b.x, c.x); r.y = fmaf(a.y, b.y, c.y); return r;
#endif
}
__device__ __forceinline__ v2f splat2(float w) { return v2f{w, w}; }
__device__ __forceinline__ v2f relu2(v2f a) { return v2f{fmaxf(a.x, 0.f), fmaxf(a.y, 0.f)}; }

// ---- LDS weight arena with per-gate bank pads (R0-verified layout) ----------
// Each gate block is 20*IN + 4 floats: the wave's two concurrent row addresses
// (s=0: gates i/f, s=1: o/g) land on disjoint bank quads.
constexpr int BLK16 = 20 * 16 + 4;   // 324
constexpr int BLK20 = 20 * 20 + 4;   // 404
constexpr int BLK4  = 20 * 4 + 4;    // 84

constexpr int W_Wih1_0 = 0;
constexpr int W_Whh1_0 = W_Wih1_0 + 4 * BLK16;    // 1296
constexpr int W_b1_0   = W_Whh1_0 + 4 * BLK20;    // 2912
constexpr int W_Wih1_1 = W_b1_0 + 80;             // 2992
constexpr int W_Whh1_1 = W_Wih1_1 + 4 * BLK20;    // 4608
constexpr int W_b1_1   = W_Whh1_1 + 4 * BLK20;    // 6224
constexpr int W_Wih2_0 = W_b1_1 + 80;             // 6304
constexpr int W_Whh2_0 = W_Wih2_0 + 4 * BLK4;     // 6640
constexpr int W_b2_0   = W_Whh2_0 + 4 * BLK20;    // 8256
constexpr int W_Wih2_1 = W_b2_0 + 80;             // 8336
constexpr int W_Whh2_1 = W_Wih2_1 + 4 * BLK20;    // 9952
constexpr int W_b2_1   = W_Whh2_1 + 4 * BLK20;    // 11568
constexpr int W_fW1    = W_b2_1 + 80;             // 11648
constexpr int W_fb1    = W_fW1 + 200;             // 11848
constexpr int W_fW2    = W_fb1 + 12;              // 11860
constexpr int W_fb2    = W_fW2 + 100;             // 11960
constexpr int W_fW3    = W_fb2 + 12;              // 11972
constexpr int W_fb3    = W_fW3 + 10;              // 11982
constexpr int LDS_TOT  = W_fb3 + 2;               // 11984 floats = 47.9 KB

// One float4 weight chunk feeds BOTH element-pairs: 8 pk-fma = 16 scalar FMAs
// per 16B LDS read (2x the R0 amortization).
template <int IN, size_t U, size_t K>
__device__ __forceinline__ void row2x_k(const float (&sm)[LDS_TOT], int rb,
                                        const v2f (&p0)[IN], const v2f (&p1)[IN],
                                        v2f& a0, v2f& a1) {
    float4 w = *(const float4*)&sm[rb + (int)(U * IN + 4 * K)];
    v2f w0 = splat2(w.x), w1 = splat2(w.y), w2 = splat2(w.z), w3 = splat2(w.w);
    a0 = fma2(w0, p0[4 * K + 0], a0);  a1 = fma2(w0, p1[4 * K + 0], a1);
    a0 = fma2(w1, p0[4 * K + 1], a0);  a1 = fma2(w1, p1[4 * K + 1], a1);
    a0 = fma2(w2, p0[4 * K + 2], a0);  a1 = fma2(w2, p1[4 * K + 2], a1);
    a0 = fma2(w3, p0[4 * K + 3], a0);  a1 = fma2(w3, p1[4 * K + 3], a1);
}
template <int IN, size_t U, size_t... K>
__device__ __forceinline__ void row2x(const float (&sm)[LDS_TOT], int rb,
                                      const v2f (&p0)[IN], const v2f (&p1)[IN],
                                      v2f& a0, v2f& a1, std::index_sequence<K...>) {
    (row2x_k<IN, U, K>(sm, rb, p0, p1, a0, a1), ...);
}

// One LSTM unit, gate-split across a lane pair, 2 elements per lane.
// s=0 lane: rows A=i, B=f (m=1 -> B act = sigma); s=1: A=o, B=g (m=2 -> tanh).
// p0/p1 are (own, oth) pairs for element 0 / element 1.
template <int IN, size_t U>
__device__ __forceinline__ void unit2x(const float (&sm)[LDS_TOT], int s, float m, float mm1,
                                       int wihA, int wihB, int whhA, int whhB, int bA, int bB,
                                       const v2f (&xp0)[IN], const v2f (&xp1)[IN],
                                       const v2f (&hp0)[HH], const v2f (&hp1)[HH],
                                       v2f (&c_own)[HH], v2f (&hn)[HH]) {
    float bAv = sm[bA + (int)U];
    float bBv = sm[bB + (int)U];
    v2f aA0 = splat2(bAv), aA1 = splat2(bAv);
    v2f aB0 = splat2(bBv), aB1 = splat2(bBv);
    row2x<IN, U>(sm, wihA, xp0, xp1, aA0, aA1, std::make_index_sequence<IN / 4>{});
    row2x<IN, U>(sm, wihB, xp0, xp1, aB0, aB1, std::make_index_sequence<IN / 4>{});
    row2x<HH, U>(sm, whhA, hp0, hp1, aA0, aA1, std::make_index_sequence<HH / 4>{});
    row2x<HH, U>(sm, whhB, hp0, hp1, aB0, aB1, std::make_index_sequence<HH / 4>{});
    float cn0, cn1;
    {   // element 0
        float Ao = fsigmoid(aA0.x), At = fsigmoid(aA0.y);
        float Bo = fmaf(m, fsigmoid(m * aB0.x), -mm1);
        float Bt = fmaf(m, fsigmoid(m * aB0.y), -mm1);
        float rA = pswap(At);
        float rB = pswap(Bt);
        float sf = s ? rB : Bo;
        float si = s ? rA : Ao;
        float tg = s ? Bo : rB;
        float so = s ? Ao : rA;
        cn0 = fmaf(sf, c_own[U].x, si * tg);
        hn[U].x = so * ftanh(cn0);
    }
    {   // element 1
        float Ao = fsigmoid(aA1.x), At = fsigmoid(aA1.y);
        float Bo = fmaf(m, fsigmoid(m * aB1.x), -mm1);
        float Bt = fmaf(m, fsigmoid(m * aB1.y), -mm1);
        float rA = pswap(At);
        float rB = pswap(Bt);
        float sf = s ? rB : Bo;
        float si = s ? rA : Ao;
        float tg = s ? Bo : rB;
        float so = s ? Ao : rA;
        cn1 = fmaf(sf, c_own[U].y, si * tg);
        hn[U].y = so * ftanh(cn1);
    }
    c_own[U] = v2f{cn0, cn1};
}

template <int WIH, int WHH, int BOFF, int IN, int BLK, size_t... U, size_t... K>
__device__ __forceinline__ void cell_impl(const float (&sm)[LDS_TOT], int wb, int s,
                                          float m, float mm1,
                                          const v2f (&xo)[IN],
                                          v2f (&h_own)[HH], v2f (&c_own)[HH],
                                          std::index_sequence<U...>, std::index_sequence<K...>) {
    // (own, oth) pairs formed once per cell (DPP on the VALU pipe), reused by
    // all 20 units x 2 rows x 2 elements.
    v2f xp0[IN], xp1[IN], hp0[HH], hp1[HH];
    ((xp0[K] = v2f{xo[K].x, pswap(xo[K].x)},
      xp1[K] = v2f{xo[K].y, pswap(xo[K].y)}), ...);
    ((hp0[U] = v2f{h_own[U].x, pswap(h_own[U].x)},
      hp1[U] = v2f{h_own[U].y, pswap(h_own[U].y)}), ...);
    const int gA = s ? 3 : 0, gB = s ? 2 : 1;
    int wihA = wb + WIH + gA * BLK;
    int wihB = wb + WIH + gB * BLK;
    int whhA = wb + WHH + gA * BLK20;
    int whhB = wb + WHH + gB * BLK20;
    int bA = wb + BOFF + gA * 20;
    int bB = wb + BOFF + gB * 20;
    v2f hn[HH];
    (unit2x<IN, U>(sm, s, m, mm1, wihA, wihB, whhA, whhB, bA, bB,
                   xp0, xp1, hp0, hp1, c_own, hn), ...);
    ((h_own[U] = hn[U]), ...);
}

template <int WIH, int WHH, int BOFF, int IN, int BLK>
__device__ __forceinline__ void cell(const float (&sm)[LDS_TOT], int wb, int s,
                                     float m, float mm1, const v2f (&xo)[IN],
                                     v2f (&h_own)[HH], v2f (&c_own)[HH]) {
    cell_impl<WIH, WHH, BOFF, IN, BLK>(sm, wb, s, m, mm1, xo, h_own, c_own,
                                       std::make_index_sequence<HH>{},
                                       std::make_index_sequence<IN>{});
}

// ---- MLP head: uniform-weight broadcast x v2f (2-element) features ----------
template <int NF, size_t... K>
__device__ __forceinline__ v2f vdot_i(const float (&sm)[LDS_TOT], int base,
                                      const v2f (&p)[NF], v2f acc, std::index_sequence<K...>) {
    ((acc = fma2(splat2(sm[base + (int)K]), p[K], acc)), ...);
    return acc;
}
template <int NF>
__device__ __forceinline__ v2f vdot(const float (&sm)[LDS_TOT], int base,
                                    const v2f (&p)[NF], v2f acc) {
    return vdot_i<NF>(sm, base, p, acc, std::make_index_sequence<NF>{});
}
template <int WOFF, int BOFF, int NF, int LD, size_t... J>
__device__ __forceinline__ void mlp_layer(const float (&sm)[LDS_TOT], int z,
                                          const v2f (&p)[NF], v2f (&o)[10],
                                          std::index_sequence<J...>) {
    ((o[J] = relu2(vdot<NF>(sm, z + WOFF + (int)J * LD, p,
                            splat2(sm[z + BOFF + (int)J])))), ...);
}

__global__ void __launch_bounds__(128, 1) lstm_ar_kernel(
    const float* __restrict__ y_past, const float* __restrict__ x_past,
    const float* __restrict__ u_past, const float* __restrict__ s_past,
    const float* __restrict__ u_future,
    const float* __restrict__ Wih1_0, const float* __restrict__ Whh1_0, const float* __restrict__ b1_0,
    const float* __restrict__ Wih1_1, const float* __restrict__ Whh1_1, const float* __restrict__ b1_1,
    const float* __restrict__ Wih2_0, const float* __restrict__ Whh2_0, const float* __restrict__ b2_0,
    const float* __restrict__ Wih2_1, const float* __restrict__ Whh2_1, const float* __restrict__ b2_1,
    const float* __restrict__ fW1, const float* __restrict__ fb1,
    const float* __restrict__ fW2, const float* __restrict__ fb2,
    const float* __restrict__ fW3, const float* __restrict__ fb3,
    float* __restrict__ out, int B) {
    __shared__ __align__(16) float smem[LDS_TOT];
    const int tid = threadIdx.x;

    // ---- stage weights into LDS with per-gate +4 pads (R0-identical) ----
    auto stage_w = [&](const float* src, int off, int IN) {
        const int gb = 20 * IN;
        for (int i = tid; i < 4 * gb; i += 128) {
            int g = i / gb;
            smem[off + g * (gb + 4) + (i - g * gb)] = src[i];
        }
    };
    auto stage = [&](const float* src, int off, int n) {
        for (int i = tid; i < n; i += 128) smem[off + i] = src[i];
    };
    stage_w(Wih1_0, W_Wih1_0, 16);
    stage_w(Whh1_0, W_Whh1_0, 20);
    stage(b1_0, W_b1_0, 80);
    stage_w(Wih1_1, W_Wih1_1, 20);
    stage_w(Whh1_1, W_Whh1_1, 20);
    stage(b1_1, W_b1_1, 80);
    stage_w(Wih2_0, W_Wih2_0, 4);
    stage_w(Whh2_0, W_Whh2_0, 20);
    stage(b2_0, W_b2_0, 80);
    stage_w(Wih2_1, W_Wih2_1, 20);
    stage_w(Whh2_1, W_Whh2_1, 20);
    stage(b2_1, W_b2_1, 80);
    stage(fW1, W_fW1, 200);
    stage(fb1, W_fb1, 10);
    stage(fW2, W_fW2, 100);
    stage(fb2, W_fb2, 10);
    stage(fW3, W_fW3, 10);
    stage(fb3, W_fb3, 1);
    __syncthreads();

    const int s = tid & 1;                    // gate half: 0 -> (i,f), 1 -> (o,g)
    const int half = B >> 1;                  // B % 256 == 0
    const int g = blockIdx.x * 128 + tid;
    if (g >= half) return;                    // never taken
    const int e0 = g;                         // own elements: (g, g + B/2)
    const int e1 = g + half;                  // both streams stride-1 coalesced

    const float m   = s ? 2.0f : 1.0f;
    const float mm1 = m - 1.0f;

    // own-element state, 2 elements per lane: 160 registers
    v2f h0[HH], c0[HH], h1[HH], c1[HH];
    {
        auto zero = [&](auto... u) {
            ((h0[u] = v2f{0.f, 0.f}, c0[u] = v2f{0.f, 0.f},
              h1[u] = v2f{0.f, 0.f}, c1[u] = v2f{0.f, 0.f}), ...);
        };
        zero(0, 1, 2, 3, 4, 5, 6, 7, 8, 9, 10, 11, 12, 13, 14, 15, 16, 17, 18, 19);
    }

    int wb = 0;  // laundered weight base: re-opaqued per timestep (kills LICM hoist)

    // ---- encoder over lookback T=8 (input = concat[y,x,u,s] = 16 feats) ----
#pragma clang loop unroll(disable)
    for (int t = 0; t < 8; ++t) {
        asm volatile("" : "+s"(wb));
        v2f x[16];
        {
            float a = y_past[e0 * 8 + t];
            float b = y_past[e1 * 8 + t];
            x[0] = v2f{a, b};
        }
        {
            const float4* pa = (const float4*)(x_past + (size_t)(e0 * 8 + t) * 8);
            const float4* pb = (const float4*)(x_past + (size_t)(e1 * 8 + t) * 8);
            float4 a0 = pa[0], a1 = pa[1], b0 = pb[0], b1 = pb[1];
            x[1] = v2f{a0.x, b0.x}; x[2] = v2f{a0.y, b0.y};
            x[3] = v2f{a0.z, b0.z}; x[4] = v2f{a0.w, b0.w};
            x[5] = v2f{a1.x, b1.x}; x[6] = v2f{a1.y, b1.y};
            x[7] = v2f{a1.z, b1.z}; x[8] = v2f{a1.w, b1.w};
        }
        {
            const float4* pa = (const float4*)(u_past + (size_t)(e0 * 8 + t) * 4);
            const float4* pb = (const float4*)(u_past + (size_t)(e1 * 8 + t) * 4);
            float4 a0 = pa[0], b0 = pb[0];
            x[9]  = v2f{a0.x, b0.x}; x[10] = v2f{a0.y, b0.y};
            x[11] = v2f{a0.z, b0.z}; x[12] = v2f{a0.w, b0.w};
        }
        {
            const float* pa = s_past + (size_t)(e0 * 8 + t) * 3;
            const float* pb = s_past + (size_t)(e1 * 8 + t) * 3;
            x[13] = v2f{pa[0], pb[0]};
            x[14] = v2f{pa[1], pb[1]};
            x[15] = v2f{pa[2], pb[2]};
        }
        cell<W_Wih1_0, W_Whh1_0, W_b1_0, 16, BLK16>(smem, wb, s, m, mm1, x, h0, c0);
        cell<W_Wih1_1, W_Whh1_1, W_b1_1, HH, BLK20>(smem, wb, s, m, mm1, h0, h1, c1);
    }

    // ---- decoder over lookahead T=4 (input = u_future, 4 feats) + MLP head ----
#pragma clang loop unroll(disable)
    for (int t = 0; t < 4; ++t) {
        asm volatile("" : "+s"(wb));
        v2f x[4];
        {
            const float4* pa = (const float4*)(u_future + (size_t)(e0 * 4 + t) * 4);
            const float4* pb = (const float4*)(u_future + (size_t)(e1 * 4 + t) * 4);
            float4 a0 = pa[0], b0 = pb[0];
            x[0] = v2f{a0.x, b0.x}; x[1] = v2f{a0.y, b0.y};
            x[2] = v2f{a0.z, b0.z}; x[3] = v2f{a0.w, b0.w};
        }
        cell<W_Wih2_0, W_Whh2_0, W_b2_0, 4, BLK4>(smem, wb, s, m, mm1, x, h0, c0);
        cell<W_Wih2_1, W_Whh2_1, W_b2_1, HH, BLK20>(smem, wb, s, m, mm1, h0, h1, c1);

        // FCNN 20 -> 10 -> 10 -> 1 on OWN elements' h1 (v2f halves)
        v2f z1[10], z2[10];
        mlp_layer<W_fW1, W_fb1, HH, HH>(smem, wb, h1, z1, std::make_index_sequence<10>{});
        mlp_layer<W_fW2, W_fb2, 10, 10>(smem, wb, z1, z2, std::make_index_sequence<10>{});
        v2f o = vdot<10>(smem, wb + W_fW3, z2, splat2(smem[wb + W_fb3]));
        out[e0 * 4 + t] = o.x;
        out[e1 * 4 + t] = o.y;
    }
}

extern "C" void kernel_launch(void* const* d_in, const int* in_sizes, int n_in,
                              void* d_out, int out_size, void* d_ws, size_t ws_size,
                              hipStream_t stream) {
    (void)n_in; (void)d_ws; (void)ws_size;
    const float* y_past   = (const float*)d_in[0];
    const float* x_past   = (const float*)d_in[1];
    const float* u_past   = (const float*)d_in[2];
    const float* s_past   = (const float*)d_in[3];
    const float* u_future = (const float*)d_in[4];
    const float* Wih1_0 = (const float*)d_in[5];
    const float* Whh1_0 = (const float*)d_in[6];
    const float* b1_0   = (const float*)d_in[7];
    const float* Wih1_1 = (const float*)d_in[8];
    const float* Whh1_1 = (const float*)d_in[9];
    const float* b1_1   = (const float*)d_in[10];
    const float* Wih2_0 = (const float*)d_in[11];
    const float* Whh2_0 = (const float*)d_in[12];
    const float* b2_0   = (const float*)d_in[13];
    const float* Wih2_1 = (const float*)d_in[14];
    const float* Whh2_1 = (const float*)d_in[15];
    const float* b2_1   = (const float*)d_in[16];
    const float* fW1 = (const float*)d_in[17];
    const float* fb1 = (const float*)d_in[18];
    const float* fW2 = (const float*)d_in[19];
    const float* fb2 = (const float*)d_in[20];
    const float* fW3 = (const float*)d_in[21];
    const float* fb3 = (const float*)d_in[22];
    float* out = (float*)d_out;

    int B = in_sizes[0] / 8;  // y_past is [B,8,1]
    (void)out_size;

    int nthreads = B / 2;     // 2 elements per thread
    dim3 block(128);
    dim3 grid((nthreads + 127) / 128);
    lstm_ar_kernel<<<grid, block, 0, stream>>>(
        y_past, x_past, u_past, s_past, u_future,
        Wih1_0, Whh1_0, b1_0, Wih1_1, Whh1_1, b1_1,
        Wih2_0, Whh2_0, b2_0, Wih2_1, Whh2_1, b2_1,
        fW1, fb1, fW2, fb2, fW3, fb3, out, B);
}

// Round 4
// 587.913 us; speedup vs baseline: 1.4552x; 1.0735x over previous
//
#include <hip/hip_runtime.h>
#include <utility>

#define HH 20

typedef float v2f __attribute__((ext_vector_type(2)));

// Raw v_rcp_f32 (~1 ulp); harness threshold 1.9e-3.
__device__ __forceinline__ float fast_rcp(float x) { return __builtin_amdgcn_rcpf(x); }
__device__ __forceinline__ float fsigmoid(float x) { return fast_rcp(1.0f + __expf(-x)); }
__device__ __forceinline__ float ftanh(float x) {
    float e = __expf(2.0f * x);
    return 1.0f - 2.0f * fast_rcp(e + 1.0f);
}
// DPP quad_perm XOR patterns within each aligned 4-lane quad (VALU pipe).
constexpr int XOR1 = 0xB1;  // [1,0,3,2]
constexpr int XOR2 = 0x4E;  // [2,3,0,1]
constexpr int XOR3 = 0x1B;  // [3,2,1,0]
template <int CTRL>
__device__ __forceinline__ float qdpp(float v) {
    return __int_as_float(__builtin_amdgcn_mov_dpp(__float_as_int(v), CTRL, 0xF, 0xF, true));
}
// v_pk_fma_f32: two independent IEEE fp32 FMAs per instruction.
__device__ __forceinline__ v2f fma2(v2f a, v2f b, v2f c) {
#if __has_builtin(__builtin_elementwise_fma)
    return __builtin_elementwise_fma(a, b, c);
#else
    v2f r; r.x = fmaf(a.x, b.x, c.x); r.y = fmaf(a.y, b.y, c.y); return r;
#endif
}
__device__ __forceinline__ v2f splat2(float w) { return v2f{w, w}; }

// ---- LDS weight arena with per-gate bank pads (R0-verified layout) ----------
// Gate block g at offset g*(20*IN+4): the wave's four concurrent gate-row
// addresses land on disjoint bank quads (checked mod-32-bank arithmetic for
// BLK16/BLK20/BLK4).
constexpr int BLK16 = 20 * 16 + 4;   // 324
constexpr int BLK20 = 20 * 20 + 4;   // 404
constexpr int BLK4  = 20 * 4 + 4;    // 84

constexpr int W_Wih1_0 = 0;
constexpr int W_Whh1_0 = W_Wih1_0 + 4 * BLK16;    // 1296
constexpr int W_b1_0   = W_Whh1_0 + 4 * BLK20;    // 2912
constexpr int W_Wih1_1 = W_b1_0 + 80;             // 2992
constexpr int W_Whh1_1 = W_Wih1_1 + 4 * BLK20;    // 4608
constexpr int W_b1_1   = W_Whh1_1 + 4 * BLK20;    // 6224
constexpr int W_Wih2_0 = W_b1_1 + 80;             // 6304
constexpr int W_Whh2_0 = W_Wih2_0 + 4 * BLK4;     // 6640
constexpr int W_b2_0   = W_Whh2_0 + 4 * BLK20;    // 8256
constexpr int W_Wih2_1 = W_b2_0 + 80;             // 8336
constexpr int W_Whh2_1 = W_Wih2_1 + 4 * BLK20;    // 9952
constexpr int W_b2_1   = W_Whh2_1 + 4 * BLK20;    // 11568
constexpr int W_fW1    = W_b2_1 + 80;             // 11648
constexpr int W_fb1    = W_fW1 + 200;             // 11848
constexpr int W_fW2    = W_fb1 + 12;              // 11860
constexpr int W_fb2    = W_fW2 + 100;             // 11960
constexpr int W_fW3    = W_fb2 + 12;              // 11972
constexpr int W_fb3    = W_fW3 + 10;              // 11982
constexpr int LDS_TOT  = W_fb3 + 2;               // 11984 floats = 47.9 KB

// One float4 weight chunk (lane's own gate row) feeds 4 quad elements:
// 8 pk-fma = 16 scalar FMAs per 16B LDS read.
template <int IN, size_t U, size_t K>
__device__ __forceinline__ void rowq_k(const float (&sm)[LDS_TOT], int rb,
                                       const v2f (&p01)[IN], const v2f (&p23)[IN],
                                       v2f& a01, v2f& a23) {
    float4 w = *(const float4*)&sm[rb + (int)(U * IN + 4 * K)];
    v2f w0 = splat2(w.x), w1 = splat2(w.y), w2 = splat2(w.z), w3 = splat2(w.w);
    a01 = fma2(w0, p01[4 * K + 0], a01);  a23 = fma2(w0, p23[4 * K + 0], a23);
    a01 = fma2(w1, p01[4 * K + 1], a01);  a23 = fma2(w1, p23[4 * K + 1], a23);
    a01 = fma2(w2, p01[4 * K + 2], a01);  a23 = fma2(w2, p23[4 * K + 2], a23);
    a01 = fma2(w3, p01[4 * K + 3], a01);  a23 = fma2(w3, p23[4 * K + 3], a23);
}
template <int IN, size_t U, size_t... K>
__device__ __forceinline__ void rowq(const float (&sm)[LDS_TOT], int rb,
                                     const v2f (&p01)[IN], const v2f (&p23)[IN],
                                     v2f& a01, v2f& a23, std::index_sequence<K...>) {
    (rowq_k<IN, U, K>(sm, rb, p01, p23, a01, a23), ...);
}

// One LSTM unit, quad-split: lane q computes gate q (i=0,f=1,g=2,o=3) for the
// quad's 4 elements in LOCAL order (own, q^1, q^2, q^3). Operand quads are in
// local order too, so the weight splat is order-agnostic. The gather-back of
// own-element gates uses fixed components (local order makes them
// lane-independent): c_k = qdpp<XORk>(act at local slot k).
template <int IN, size_t U>
__device__ __forceinline__ void unitq(const float (&sm)[LDS_TOT], bool q0, bool q1,
                                      float m, float mm1, int rih, int rhh, int rb,
                                      const v2f (&xp01)[IN], const v2f (&xp23)[IN],
                                      const v2f (&hp01)[HH], const v2f (&hp23)[HH],
                                      float (&c)[HH], float (&hn)[HH]) {
    float bv = sm[rb + (int)U];
    v2f a01 = splat2(bv), a23 = splat2(bv);
    rowq<IN, U>(sm, rih, xp01, xp23, a01, a23, std::make_index_sequence<IN / 4>{});
    rowq<HH, U>(sm, rhh, hp01, hp23, a01, a23, std::make_index_sequence<HH / 4>{});
    // m-trick activation (R0-verified): m=1 -> sigma, m=2 -> tanh
    float act0 = fmaf(m, fsigmoid(m * a01.x), -mm1);
    float act1 = fmaf(m, fsigmoid(m * a01.y), -mm1);
    float act2 = fmaf(m, fsigmoid(m * a23.x), -mm1);
    float act3 = fmaf(m, fsigmoid(m * a23.y), -mm1);
    // gather own element's four gates: c_k = gate (q^k) of own element
    float c0 = act0;
    float c1 = qdpp<XOR1>(act1);
    float c2 = qdpp<XOR2>(act2);
    float c3 = qdpp<XOR3>(act3);
    // role un-permute (XOR by q, 2 stages of 4 cndmask) -- verified for q=0..3
    float u0 = q0 ? c1 : c0, u1 = q0 ? c0 : c1, u2 = q0 ? c3 : c2, u3 = q0 ? c2 : c3;
    float si = q1 ? u2 : u0, sf = q1 ? u3 : u1, tg = q1 ? u0 : u2, so = q1 ? u1 : u3;
    float cn = fmaf(sf, c[U], si * tg);
    c[U] = cn;
    hn[U] = so * ftanh(cn);
}

template <int WIH, int WHH, int BOFF, int IN, int BLK, size_t... U, size_t... K>
__device__ __forceinline__ void cell_impl(const float (&sm)[LDS_TOT], int wb, int q,
                                          bool q0, bool q1, float m, float mm1,
                                          const float (&x)[IN],
                                          float (&h)[HH], float (&c)[HH],
                                          std::index_sequence<U...>, std::index_sequence<K...>) {
    // quad operand vectors in local order: (own, q^1 | q^2, q^3); 3 DPP/scalar
    v2f xp01[IN], xp23[IN], hp01[HH], hp23[HH];
    ((xp01[K] = v2f{x[K], qdpp<XOR1>(x[K])},
      xp23[K] = v2f{qdpp<XOR2>(x[K]), qdpp<XOR3>(x[K])}), ...);
    ((hp01[U] = v2f{h[U], qdpp<XOR1>(h[U])},
      hp23[U] = v2f{qdpp<XOR2>(h[U]), qdpp<XOR3>(h[U])}), ...);
    const int rih = wb + WIH + q * BLK;    // own gate's row blocks (per-lane addr)
    const int rhh = wb + WHH + q * BLK20;
    const int rb  = wb + BOFF + q * 20;
    float hn[HH];
    (unitq<IN, U>(sm, q0, q1, m, mm1, rih, rhh, rb,
                  xp01, xp23, hp01, hp23, c, hn), ...);
    ((h[U] = hn[U]), ...);
}

template <int WIH, int WHH, int BOFF, int IN, int BLK>
__device__ __forceinline__ void cell(const float (&sm)[LDS_TOT], int wb, int q,
                                     bool q0, bool q1, float m, float mm1,
                                     const float (&x)[IN],
                                     float (&h)[HH], float (&c)[HH]) {
    cell_impl<WIH, WHH, BOFF, IN, BLK>(sm, wb, q, q0, q1, m, mm1, x, h, c,
                                       std::make_index_sequence<HH>{},
                                       std::make_index_sequence<IN>{});
}

// ---- MLP: R0-identical serial structure (own element, uniform LDS reads) ----
template <int WOFF, size_t J, int LD, int NV, size_t... K>
__device__ __forceinline__ float mlp_dot(const float (&sm)[LDS_TOT], int wb, const float (&v)[NV],
                                         float a, std::index_sequence<K...>) {
    ((a = fmaf(sm[wb + WOFF + (int)(J * LD + K)], v[K], a)), ...);
    return a;
}
template <size_t... J>
__device__ __forceinline__ void mlp_l1(const float (&sm)[LDS_TOT], int wb,
                                       const float (&h)[HH], float (&z)[10], std::index_sequence<J...>) {
    ((z[J] = fmaxf(mlp_dot<W_fW1, J, HH>(sm, wb, h, sm[wb + W_fb1 + (int)J],
                                         std::make_index_sequence<HH>{}), 0.f)), ...);
}
template <size_t... J>
__device__ __forceinline__ void mlp_l2(const float (&sm)[LDS_TOT], int wb,
                                       const float (&z1)[10], float (&z2)[10], std::index_sequence<J...>) {
    ((z2[J] = fmaxf(mlp_dot<W_fW2, J, 10>(sm, wb, z1, sm[wb + W_fb2 + (int)J],
                                          std::make_index_sequence<10>{}), 0.f)), ...);
}

__global__ void __launch_bounds__(256, 2) lstm_ar_kernel(
    const float* __restrict__ y_past, const float* __restrict__ x_past,
    const float* __restrict__ u_past, const float* __restrict__ s_past,
    const float* __restrict__ u_future,
    const float* __restrict__ Wih1_0, const float* __restrict__ Whh1_0, const float* __restrict__ b1_0,
    const float* __restrict__ Wih1_1, const float* __restrict__ Whh1_1, const float* __restrict__ b1_1,
    const float* __restrict__ Wih2_0, const float* __restrict__ Whh2_0, const float* __restrict__ b2_0,
    const float* __restrict__ Wih2_1, const float* __restrict__ Whh2_1, const float* __restrict__ b2_1,
    const float* __restrict__ fW1, const float* __restrict__ fb1,
    const float* __restrict__ fW2, const float* __restrict__ fb2,
    const float* __restrict__ fW3, const float* __restrict__ fb3,
    float* __restrict__ out, int B) {
    __shared__ __align__(16) float smem[LDS_TOT];
    const int tid = threadIdx.x;

    // ---- stage weights into LDS with per-gate +4 pads (R0-identical) ----
    auto stage_w = [&](const float* src, int off, int IN) {
        const int gb = 20 * IN;
        for (int i = tid; i < 4 * gb; i += 256) {
            int g = i / gb;
            smem[off + g * (gb + 4) + (i - g * gb)] = src[i];
        }
    };
    auto stage = [&](const float* src, int off, int n) {
        for (int i = tid; i < n; i += 256) smem[off + i] = src[i];
    };
    stage_w(Wih1_0, W_Wih1_0, 16);
    stage_w(Whh1_0, W_Whh1_0, 20);
    stage(b1_0, W_b1_0, 80);
    stage_w(Wih1_1, W_Wih1_1, 20);
    stage_w(Whh1_1, W_Whh1_1, 20);
    stage(b1_1, W_b1_1, 80);
    stage_w(Wih2_0, W_Wih2_0, 4);
    stage_w(Whh2_0, W_Whh2_0, 20);
    stage(b2_0, W_b2_0, 80);
    stage_w(Wih2_1, W_Wih2_1, 20);
    stage_w(Whh2_1, W_Whh2_1, 20);
    stage(b2_1, W_b2_1, 80);
    stage(fW1, W_fW1, 200);
    stage(fb1, W_fb1, 10);
    stage(fW2, W_fW2, 100);
    stage(fb2, W_fb2, 10);
    stage(fW3, W_fW3, 10);
    stage(fb3, W_fb3, 1);
    __syncthreads();

    const int q = tid & 3;                    // quad lane: gate i/f/g/o
    const bool q0 = (tid & 1) != 0;
    const bool q1 = (tid & 2) != 0;
    const int e = blockIdx.x * 256 + tid;     // OWN element == global thread id
    if (e >= B) return;                       // never taken (B % 256 == 0)

    const float m   = (q == 2) ? 2.0f : 1.0f; // tanh for the cell gate
    const float mm1 = m - 1.0f;

    // own-element state only: 80 registers
    float h0[HH], c0[HH], h1[HH], c1[HH];
    {
        auto zero = [&](auto... u) {
            ((h0[u] = 0.f, c0[u] = 0.f, h1[u] = 0.f, c1[u] = 0.f), ...);
        };
        zero(0, 1, 2, 3, 4, 5, 6, 7, 8, 9, 10, 11, 12, 13, 14, 15, 16, 17, 18, 19);
    }

    int wb = 0;  // laundered weight base: re-opaqued per timestep (kills LICM hoist)

    // ---- encoder over lookback T=8 (input = concat[y,x,u,s] = 16 feats) ----
#pragma clang loop unroll(disable)
    for (int t = 0; t < 8; ++t) {
        asm volatile("" : "+s"(wb));
        float x[16];
        x[0] = y_past[e * 8 + t];
        {
            const float4* p = (const float4*)(x_past + (size_t)(e * 8 + t) * 8);
            float4 a0 = p[0], a1 = p[1];
            x[1] = a0.x; x[2] = a0.y; x[3] = a0.z; x[4] = a0.w;
            x[5] = a1.x; x[6] = a1.y; x[7] = a1.z; x[8] = a1.w;
        }
        {
            const float4* p = (const float4*)(u_past + (size_t)(e * 8 + t) * 4);
            float4 a0 = p[0];
            x[9] = a0.x; x[10] = a0.y; x[11] = a0.z; x[12] = a0.w;
        }
        {
            const float* p = s_past + (size_t)(e * 8 + t) * 3;
            x[13] = p[0]; x[14] = p[1]; x[15] = p[2];
        }
        cell<W_Wih1_0, W_Whh1_0, W_b1_0, 16, BLK16>(smem, wb, q, q0, q1, m, mm1, x, h0, c0);
        cell<W_Wih1_1, W_Whh1_1, W_b1_1, HH, BLK20>(smem, wb, q, q0, q1, m, mm1, h0, h1, c1);
    }

    // ---- decoder over lookahead T=4 (input = u_future, 4 feats) + MLP head ----
#pragma clang loop unroll(disable)
    for (int t = 0; t < 4; ++t) {
        asm volatile("" : "+s"(wb));
        float x[4];
        {
            const float4* p = (const float4*)(u_future + (size_t)(e * 4 + t) * 4);
            float4 a0 = p[0];
            x[0] = a0.x; x[1] = a0.y; x[2] = a0.z; x[3] = a0.w;
        }
        cell<W_Wih2_0, W_Whh2_0, W_b2_0, 4, BLK4>(smem, wb, q, q0, q1, m, mm1, x, h0, c0);
        cell<W_Wih2_1, W_Whh2_1, W_b2_1, HH, BLK20>(smem, wb, q, q0, q1, m, mm1, h0, h1, c1);

        // FCNN 20 -> 10 -> 10 -> 1 on OWN element's h1
        float z1[10], z2[10];
        mlp_l1(smem, wb, h1, z1, std::make_index_sequence<10>{});
        mlp_l2(smem, wb, z1, z2, std::make_index_sequence<10>{});
        float o = mlp_dot<W_fW3, 0, 10>(smem, wb, z2, smem[wb + W_fb3],
                                        std::make_index_sequence<10>{});
        out[e * 4 + t] = o;
    }
}

extern "C" void kernel_launch(void* const* d_in, const int* in_sizes, int n_in,
                              void* d_out, int out_size, void* d_ws, size_t ws_size,
                              hipStream_t stream) {
    (void)n_in; (void)d_ws; (void)ws_size;
    const float* y_past   = (const float*)d_in[0];
    const float* x_past   = (const float*)d_in[1];
    const float* u_past   = (const float*)d_in[2];
    const float* s_past   = (const float*)d_in[3];
    const float* u_future = (const float*)d_in[4];
    const float* Wih1_0 = (const float*)d_in[5];
    const float* Whh1_0 = (const float*)d_in[6];
    const float* b1_0   = (const float*)d_in[7];
    const float* Wih1_1 = (const float*)d_in[8];
    const float* Whh1_1 = (const float*)d_in[9];
    const float* b1_1   = (const float*)d_in[10];
    const float* Wih2_0 = (const float*)d_in[11];
    const float* Whh2_0 = (const float*)d_in[12];
    const float* b2_0   = (const float*)d_in[13];
    const float* Wih2_1 = (const float*)d_in[14];
    const float* Whh2_1 = (const float*)d_in[15];
    const float* b2_1   = (const float*)d_in[16];
    const float* fW1 = (const float*)d_in[17];
    const float* fb1 = (const float*)d_in[18];
    const float* fW2 = (const float*)d_in[19];
    const float* fb2 = (const float*)d_in[20];
    const float* fW3 = (const float*)d_in[21];
    const float* fb3 = (const float*)d_in[22];
    float* out = (float*)d_out;

    int B = in_sizes[0] / 8;  // y_past is [B,8,1]
    (void)out_size;

    dim3 block(256);
    dim3 grid((B + 255) / 256);
    lstm_ar_kernel<<<grid, block, 0, stream>>>(
        y_past, x_past, u_past, s_past, u_future,
        Wih1_0, Whh1_0, b1_0, Wih1_1, Whh1_1, b1_1,
        Wih2_0, Whh2_0, b2_0, Wih2_1, Whh2_1, b2_1,
        fW1, fb1, fW2, fb2, fW3, fb3, out, B);
}

// Round 5
// 503.136 us; speedup vs baseline: 1.7004x; 1.1685x over previous
//
#include <hip/hip_runtime.h>
#include <utility>

#define HH 20

typedef float v2f __attribute__((ext_vector_type(2)));

// Raw v_rcp_f32 (~1 ulp); harness threshold 1.9e-3.
__device__ __forceinline__ float fast_rcp(float x) { return __builtin_amdgcn_rcpf(x); }
__device__ __forceinline__ float fsigmoid(float x) { return fast_rcp(1.0f + __expf(-x)); }
__device__ __forceinline__ float ftanh(float x) {
    float e = __expf(2.0f * x);
    return 1.0f - 2.0f * fast_rcp(e + 1.0f);
}
// DPP quad_perm XOR patterns within each aligned 4-lane quad (VALU pipe).
constexpr int XOR1 = 0xB1;  // [1,0,3,2]
constexpr int XOR2 = 0x4E;  // [2,3,0,1]
constexpr int XOR3 = 0x1B;  // [3,2,1,0]
template <int CTRL>
__device__ __forceinline__ float qdpp(float v) {
    return __int_as_float(__builtin_amdgcn_mov_dpp(__float_as_int(v), CTRL, 0xF, 0xF, true));
}
// v_pk_fma_f32: two independent IEEE fp32 FMAs per instruction.
__device__ __forceinline__ v2f fma2(v2f a, v2f b, v2f c) {
#if __has_builtin(__builtin_elementwise_fma)
    return __builtin_elementwise_fma(a, b, c);
#else
    v2f r; r.x = fmaf(a.x, b.x, c.x); r.y = fmaf(a.y, b.y, c.y); return r;
#endif
}
__device__ __forceinline__ v2f splat2(float w) { return v2f{w, w}; }

// ---- LDS weight arena with per-gate bank pads (R0-verified layout) ----------
// Gate block g at offset g*(20*IN+4): the wave's four concurrent gate-row
// addresses land on disjoint bank quads (checked mod-32-bank arithmetic for
// BLK16/BLK20/BLK4).
constexpr int BLK16 = 20 * 16 + 4;   // 324
constexpr int BLK20 = 20 * 20 + 4;   // 404
constexpr int BLK4  = 20 * 4 + 4;    // 84

constexpr int W_Wih1_0 = 0;
constexpr int W_Whh1_0 = W_Wih1_0 + 4 * BLK16;    // 1296
constexpr int W_b1_0   = W_Whh1_0 + 4 * BLK20;    // 2912
constexpr int W_Wih1_1 = W_b1_0 + 80;             // 2992
constexpr int W_Whh1_1 = W_Wih1_1 + 4 * BLK20;    // 4608
constexpr int W_b1_1   = W_Whh1_1 + 4 * BLK20;    // 6224
constexpr int W_Wih2_0 = W_b1_1 + 80;             // 6304
constexpr int W_Whh2_0 = W_Wih2_0 + 4 * BLK4;     // 6640
constexpr int W_b2_0   = W_Whh2_0 + 4 * BLK20;    // 8256
constexpr int W_Wih2_1 = W_b2_0 + 80;             // 8336
constexpr int W_Whh2_1 = W_Wih2_1 + 4 * BLK20;    // 9952
constexpr int W_b2_1   = W_Whh2_1 + 4 * BLK20;    // 11568
constexpr int W_fW1    = W_b2_1 + 80;             // 11648
constexpr int W_fb1    = W_fW1 + 200;             // 11848
constexpr int W_fW2    = W_fb1 + 12;              // 11860
constexpr int W_fb2    = W_fW2 + 100;             // 11960
constexpr int W_fW3    = W_fb2 + 12;              // 11972
constexpr int W_fb3    = W_fW3 + 10;              // 11982
constexpr int LDS_TOT  = W_fb3 + 2;               // 11984 floats = 47.9 KB

// One float4 weight chunk (lane's own gate row) feeds 4 quad elements:
// 8 pk-fma = 16 scalar FMAs per 16B LDS read.
template <int IN, size_t U, size_t K>
__device__ __forceinline__ void rowq_k(const float (&sm)[LDS_TOT], int rb,
                                       const v2f (&p01)[IN], const v2f (&p23)[IN],
                                       v2f& a01, v2f& a23) {
    float4 w = *(const float4*)&sm[rb + (int)(U * IN + 4 * K)];
    v2f w0 = splat2(w.x), w1 = splat2(w.y), w2 = splat2(w.z), w3 = splat2(w.w);
    a01 = fma2(w0, p01[4 * K + 0], a01);  a23 = fma2(w0, p23[4 * K + 0], a23);
    a01 = fma2(w1, p01[4 * K + 1], a01);  a23 = fma2(w1, p23[4 * K + 1], a23);
    a01 = fma2(w2, p01[4 * K + 2], a01);  a23 = fma2(w2, p23[4 * K + 2], a23);
    a01 = fma2(w3, p01[4 * K + 3], a01);  a23 = fma2(w3, p23[4 * K + 3], a23);
}
template <int IN, size_t U, size_t... K>
__device__ __forceinline__ void rowq(const float (&sm)[LDS_TOT], int rb,
                                     const v2f (&p01)[IN], const v2f (&p23)[IN],
                                     v2f& a01, v2f& a23, std::index_sequence<K...>) {
    (rowq_k<IN, U, K>(sm, rb, p01, p23, a01, a23), ...);
}

// One LSTM unit, quad-split: lane q computes gate q (i=0,f=1,g=2,o=3) for the
// quad's 4 elements in LOCAL order (own, q^1, q^2, q^3). Operand quads are in
// local order too, so the weight splat is order-agnostic. The gather-back of
// own-element gates uses fixed components (local order makes them
// lane-independent): c_k = qdpp<XORk>(act at local slot k).
// h[U] is updated IN PLACE: all units read only the hp quad copies, so the
// old h value is dead once the quads are built (saves the hn copy-back regs).
template <int IN, size_t U>
__device__ __forceinline__ void unitq(const float (&sm)[LDS_TOT], bool q0, bool q1,
                                      float m, float mm1, int rih, int rhh, int rb,
                                      const v2f (&xp01)[IN], const v2f (&xp23)[IN],
                                      const v2f (&hp01)[HH], const v2f (&hp23)[HH],
                                      float (&c)[HH], float (&h)[HH]) {
    float bv = sm[rb + (int)U];
    v2f a01 = splat2(bv), a23 = splat2(bv);
    rowq<IN, U>(sm, rih, xp01, xp23, a01, a23, std::make_index_sequence<IN / 4>{});
    rowq<HH, U>(sm, rhh, hp01, hp23, a01, a23, std::make_index_sequence<HH / 4>{});
    // m-trick activation (R0-verified): m=1 -> sigma, m=2 -> tanh
    float act0 = fmaf(m, fsigmoid(m * a01.x), -mm1);
    float act1 = fmaf(m, fsigmoid(m * a01.y), -mm1);
    float act2 = fmaf(m, fsigmoid(m * a23.x), -mm1);
    float act3 = fmaf(m, fsigmoid(m * a23.y), -mm1);
    // gather own element's four gates: c_k = gate (q^k) of own element
    float c0 = act0;
    float c1 = qdpp<XOR1>(act1);
    float c2 = qdpp<XOR2>(act2);
    float c3 = qdpp<XOR3>(act3);
    // role un-permute (XOR by q, 2 stages of 4 cndmask) -- verified for q=0..3
    float u0 = q0 ? c1 : c0, u1 = q0 ? c0 : c1, u2 = q0 ? c3 : c2, u3 = q0 ? c2 : c3;
    float si = q1 ? u2 : u0, sf = q1 ? u3 : u1, tg = q1 ? u0 : u2, so = q1 ? u1 : u3;
    float cn = fmaf(sf, c[U], si * tg);
    c[U] = cn;
    h[U] = so * ftanh(cn);
}

template <int WIH, int WHH, int BOFF, int IN, int BLK, size_t... U, size_t... K>
__device__ __forceinline__ void cell_impl(const float (&sm)[LDS_TOT], int wb, int q,
                                          bool q0, bool q1, float m, float mm1,
                                          const float (&x)[IN],
                                          float (&h)[HH], float (&c)[HH],
                                          std::index_sequence<U...>, std::index_sequence<K...>) {
    // quad operand vectors in local order: (own, q^1 | q^2, q^3); 3 DPP/scalar
    v2f xp01[IN], xp23[IN], hp01[HH], hp23[HH];
    ((xp01[K] = v2f{x[K], qdpp<XOR1>(x[K])},
      xp23[K] = v2f{qdpp<XOR2>(x[K]), qdpp<XOR3>(x[K])}), ...);
    ((hp01[U] = v2f{h[U], qdpp<XOR1>(h[U])},
      hp23[U] = v2f{qdpp<XOR2>(h[U]), qdpp<XOR3>(h[U])}), ...);
    const int rih = wb + WIH + q * BLK;    // own gate's row blocks (per-lane addr)
    const int rhh = wb + WHH + q * BLK20;
    const int rb  = wb + BOFF + q * 20;
    (unitq<IN, U>(sm, q0, q1, m, mm1, rih, rhh, rb,
                  xp01, xp23, hp01, hp23, c, h), ...);
}

template <int WIH, int WHH, int BOFF, int IN, int BLK>
__device__ __forceinline__ void cell(const float (&sm)[LDS_TOT], int wb, int q,
                                     bool q0, bool q1, float m, float mm1,
                                     const float (&x)[IN],
                                     float (&h)[HH], float (&c)[HH]) {
    cell_impl<WIH, WHH, BOFF, IN, BLK>(sm, wb, q, q0, q1, m, mm1, x, h, c,
                                       std::make_index_sequence<HH>{},
                                       std::make_index_sequence<IN>{});
}

// ---- MLP: serial structure (own element, uniform LDS reads) -----------------
template <int WOFF, size_t J, int LD, int NV, size_t... K>
__device__ __forceinline__ float mlp_dot(const float (&sm)[LDS_TOT], int wb, const float (&v)[NV],
                                         float a, std::index_sequence<K...>) {
    ((a = fmaf(sm[wb + WOFF + (int)(J * LD + K)], v[K], a)), ...);
    return a;
}
template <size_t... J>
__device__ __forceinline__ void mlp_l1(const float (&sm)[LDS_TOT], int wb,
                                       const float (&h)[HH], float (&z)[10], std::index_sequence<J...>) {
    ((z[J] = fmaxf(mlp_dot<W_fW1, J, HH>(sm, wb, h, sm[wb + W_fb1 + (int)J],
                                         std::make_index_sequence<HH>{}), 0.f)), ...);
}
template <size_t... J>
__device__ __forceinline__ void mlp_l2(const float (&sm)[LDS_TOT], int wb,
                                       const float (&z1)[10], float (&z2)[10], std::index_sequence<J...>) {
    ((z2[J] = fmaxf(mlp_dot<W_fW2, J, 10>(sm, wb, z1, sm[wb + W_fb2 + (int)J],
                                          std::make_index_sequence<10>{}), 0.f)), ...);
}

// waves_per_eu(2,2): pin the allocator to the true reachable occupancy
// (grid = 2 blocks/CU -> 2 waves/SIMD), giving the full 256-VGPR budget.
// R4's __launch_bounds__(256,2) form capped at 128 VGPRs -> 348 MB of spill
// traffic per dispatch.
__global__ void __launch_bounds__(256)
__attribute__((amdgpu_waves_per_eu(2, 2))) lstm_ar_kernel(
    const float* __restrict__ y_past, const float* __restrict__ x_past,
    const float* __restrict__ u_past, const float* __restrict__ s_past,
    const float* __restrict__ u_future,
    const float* __restrict__ Wih1_0, const float* __restrict__ Whh1_0, const float* __restrict__ b1_0,
    const float* __restrict__ Wih1_1, const float* __restrict__ Whh1_1, const float* __restrict__ b1_1,
    const float* __restrict__ Wih2_0, const float* __restrict__ Whh2_0, const float* __restrict__ b2_0,
    const float* __restrict__ Wih2_1, const float* __restrict__ Whh2_1, const float* __restrict__ b2_1,
    const float* __restrict__ fW1, const float* __restrict__ fb1,
    const float* __restrict__ fW2, const float* __restrict__ fb2,
    const float* __restrict__ fW3, const float* __restrict__ fb3,
    float* __restrict__ out, int B) {
    __shared__ __align__(16) float smem[LDS_TOT];
    const int tid = threadIdx.x;

    // ---- stage weights into LDS with per-gate +4 pads (R0-identical) ----
    auto stage_w = [&](const float* src, int off, int IN) {
        const int gb = 20 * IN;
        for (int i = tid; i < 4 * gb; i += 256) {
            int g = i / gb;
            smem[off + g * (gb + 4) + (i - g * gb)] = src[i];
        }
    };
    auto stage = [&](const float* src, int off, int n) {
        for (int i = tid; i < n; i += 256) smem[off + i] = src[i];
    };
    stage_w(Wih1_0, W_Wih1_0, 16);
    stage_w(Whh1_0, W_Whh1_0, 20);
    stage(b1_0, W_b1_0, 80);
    stage_w(Wih1_1, W_Wih1_1, 20);
    stage_w(Whh1_1, W_Whh1_1, 20);
    stage(b1_1, W_b1_1, 80);
    stage_w(Wih2_0, W_Wih2_0, 4);
    stage_w(Whh2_0, W_Whh2_0, 20);
    stage(b2_0, W_b2_0, 80);
    stage_w(Wih2_1, W_Wih2_1, 20);
    stage_w(Whh2_1, W_Whh2_1, 20);
    stage(b2_1, W_b2_1, 80);
    stage(fW1, W_fW1, 200);
    stage(fb1, W_fb1, 10);
    stage(fW2, W_fW2, 100);
    stage(fb2, W_fb2, 10);
    stage(fW3, W_fW3, 10);
    stage(fb3, W_fb3, 1);
    __syncthreads();

    const int q = tid & 3;                    // quad lane: gate i/f/g/o
    const bool q0 = (tid & 1) != 0;
    const bool q1 = (tid & 2) != 0;
    const int e = blockIdx.x * 256 + tid;     // OWN element == global thread id
    if (e >= B) return;                       // never taken (B % 256 == 0)

    const float m   = (q == 2) ? 2.0f : 1.0f; // tanh for the cell gate
    const float mm1 = m - 1.0f;

    // own-element state only: 80 registers
    float h0[HH], c0[HH], h1[HH], c1[HH];
    {
        auto zero = [&](auto... u) {
            ((h0[u] = 0.f, c0[u] = 0.f, h1[u] = 0.f, c1[u] = 0.f), ...);
        };
        zero(0, 1, 2, 3, 4, 5, 6, 7, 8, 9, 10, 11, 12, 13, 14, 15, 16, 17, 18, 19);
    }

    int wb = 0;  // laundered weight base: re-opaqued per timestep (kills LICM hoist)

    // ---- encoder over lookback T=8 (input = concat[y,x,u,s] = 16 feats) ----
#pragma clang loop unroll(disable)
    for (int t = 0; t < 8; ++t) {
        asm volatile("" : "+s"(wb));
        float x[16];
        x[0] = y_past[e * 8 + t];
        {
            const float4* p = (const float4*)(x_past + (size_t)(e * 8 + t) * 8);
            float4 a0 = p[0], a1 = p[1];
            x[1] = a0.x; x[2] = a0.y; x[3] = a0.z; x[4] = a0.w;
            x[5] = a1.x; x[6] = a1.y; x[7] = a1.z; x[8] = a1.w;
        }
        {
            const float4* p = (const float4*)(u_past + (size_t)(e * 8 + t) * 4);
            float4 a0 = p[0];
            x[9] = a0.x; x[10] = a0.y; x[11] = a0.z; x[12] = a0.w;
        }
        {
            const float* p = s_past + (size_t)(e * 8 + t) * 3;
            x[13] = p[0]; x[14] = p[1]; x[15] = p[2];
        }
        cell<W_Wih1_0, W_Whh1_0, W_b1_0, 16, BLK16>(smem, wb, q, q0, q1, m, mm1, x, h0, c0);
        cell<W_Wih1_1, W_Whh1_1, W_b1_1, HH, BLK20>(smem, wb, q, q0, q1, m, mm1, h0, h1, c1);
    }

    // ---- decoder over lookahead T=4 (input = u_future, 4 feats) + MLP head ----
#pragma clang loop unroll(disable)
    for (int t = 0; t < 4; ++t) {
        asm volatile("" : "+s"(wb));
        float x[4];
        {
            const float4* p = (const float4*)(u_future + (size_t)(e * 4 + t) * 4);
            float4 a0 = p[0];
            x[0] = a0.x; x[1] = a0.y; x[2] = a0.z; x[3] = a0.w;
        }
        cell<W_Wih2_0, W_Whh2_0, W_b2_0, 4, BLK4>(smem, wb, q, q0, q1, m, mm1, x, h0, c0);
        cell<W_Wih2_1, W_Whh2_1, W_b2_1, HH, BLK20>(smem, wb, q, q0, q1, m, mm1, h0, h1, c1);

        // FCNN 20 -> 10 -> 10 -> 1 on OWN element's h1
        float z1[10], z2[10];
        mlp_l1(smem, wb, h1, z1, std::make_index_sequence<10>{});
        mlp_l2(smem, wb, z1, z2, std::make_index_sequence<10>{});
        float o = mlp_dot<W_fW3, 0, 10>(smem, wb, z2, smem[wb + W_fb3],
                                        std::make_index_sequence<10>{});
        out[e * 4 + t] = o;
    }
}

extern "C" void kernel_launch(void* const* d_in, const int* in_sizes, int n_in,
                              void* d_out, int out_size, void* d_ws, size_t ws_size,
                              hipStream_t stream) {
    (void)n_in; (void)d_ws; (void)ws_size;
    const float* y_past   = (const float*)d_in[0];
    const float* x_past   = (const float*)d_in[1];
    const float* u_past   = (const float*)d_in[2];
    const float* s_past   = (const float*)d_in[3];
    const float* u_future = (const float*)d_in[4];
    const float* Wih1_0 = (const float*)d_in[5];
    const float* Whh1_0 = (const float*)d_in[6];
    const float* b1_0   = (const float*)d_in[7];
    const float* Wih1_1 = (const float*)d_in[8];
    const float* Whh1_1 = (const float*)d_in[9];
    const float* b1_1   = (const float*)d_in[10];
    const float* Wih2_0 = (const float*)d_in[11];
    const float* Whh2_0 = (const float*)d_in[12];
    const float* b2_0   = (const float*)d_in[13];
    const float* Wih2_1 = (const float*)d_in[14];
    const float* Whh2_1 = (const float*)d_in[15];
    const float* b2_1   = (const float*)d_in[16];
    const float* fW1 = (const float*)d_in[17];
    const float* fb1 = (const float*)d_in[18];
    const float* fW2 = (const float*)d_in[19];
    const float* fb2 = (const float*)d_in[20];
    const float* fW3 = (const float*)d_in[21];
    const float* fb3 = (const float*)d_in[22];
    float* out = (float*)d_out;

    int B = in_sizes[0] / 8;  // y_past is [B,8,1]
    (void)out_size;

    dim3 block(256);
    dim3 grid((B + 255) / 256);
    lstm_ar_kernel<<<grid, block, 0, stream>>>(
        y_past, x_past, u_past, s_past, u_future,
        Wih1_0, Whh1_0, b1_0, Wih1_1, Whh1_1, b1_1,
        Wih2_0, Whh2_0, b2_0, Wih2_1, Whh2_1, b2_1,
        fW1, fb1, fW2, fb2, fW3, fb3, out, B);
}